// Round 9
// baseline (13.311 us; speedup 1.0000x reference)
//
#include <hip/hip_runtime.h>

typedef unsigned int u32;
typedef unsigned long long u64;

// AdderNet conv+ReLU: out[n,o,h,w] = relu(b[o] - sum_{c,kh,kw} |x - w|)
// x:[8,64,128,128] f32, w:[64,64,3,3], b:[64], out:[8,64,128,128] f32.
//
// Triangle-inequality screen over a SUBSET of terms (valid for all inputs):
//   sum_{all} |x_patch - w[o]| >= S'(n,h,w) - Wsum'[o]
// subset = channels 0..15, center input row (kh=1), in-bounds cols:
//   S'       = sum_{dc in {-1,0,1}, in-bounds} A16(n,h,w+dc)
//   A16      = sum_{c<16} |x[n,c,h,w]|
//   Wsum'[o] = sum_{c<16} sum_{kw} |w[o,c,1,kw]|   (>= subset |w| sum at edges)
// If S' >= thr = max_o(Wsum'[o]+b[o]) + 1.0 (fp32 slack), all 64 outputs at
// that pixel are exactly 0. Failing cols are recomputed exactly (fp32) by the
// owning wave, so the kernel is correct for arbitrary inputs; unit-scale
// margin ~5-7 sigma -> fix-up never taken in practice.
//
// Structure lessons baked in:
//  - r4-6: a barrier AFTER stores = full store round-trip on the critical
//    path. r8 put stores last; r9 adds PARITY STAGGER: even blocks store
//    FIRST (their one barrier eats an L2-ack drain, overlapped by other
//    waves) so the write stream overlaps the chip-wide read phase instead
//    of strictly following it (all 1024 blocks are co-resident: 4/CU).
//  - ONE barrier total: wmax + Ap partials share it; screen reads Ap
//    straight from LDS; per-wave __ballot replaces LDS nfail/flist.
//  - Per-wave store ownership (wave wid owns cols [32*wid,32*wid+32) of all
//    64 o-planes): fix-up ordering needs only the wave's own vmcnt(0).

#define Hh 128
#define Ww 128
#define C_IN 64
#define O_OUT 64
#define NB 8
#define PIX (Hh * Ww)

__global__ __launch_bounds__(256)
void adder_row_screen(const float* __restrict__ x, const float* __restrict__ w,
                      const float* __restrict__ b, float* __restrict__ out) {
    __shared__ float Ap[8 * 128];    // [g][col] partial A16 (channels g, g+8)
    __shared__ float wmax[4];

    const int tid  = threadIdx.x;
    const int bid  = blockIdx.x;
    const int n    = bid >> 7;       // image
    const int h    = bid & 127;      // row
    const int wid  = tid >> 6;
    const int lane = tid & 63;

    float4* outn = (float4*)out + (size_t)n * O_OUT * (PIX / 4);
    const float4 z = make_float4(0.f, 0.f, 0.f, 0.f);

    // wave wid zero-stores float4-cols [wid*8, wid*8+8) of row h, all 64 o
    auto do_stores = [&]() {
        const int fc = wid * 8 + (lane & 7);
        #pragma unroll
        for (int j = 0; j < 8; ++j) {
            const int o = j * 8 + (lane >> 3);
            outn[(size_t)o * (PIX / 4) + h * 32 + fc] = z;
        }
    };

    const bool even = !(bid & 1);
    if (even) do_stores();           // early write stream (drained at barrier)

    // ---- x loads: thread -> (g = tid>>5, c4 = tid&31), channels g and g+8 ----
    const int c4 = tid & 31;
    const int g  = tid >> 5;
    const float4* xn = (const float4*)x + (size_t)n * C_IN * (PIX / 4)
                     + (size_t)h * (Ww / 4) + c4;
    const float4 a0 = xn[(size_t)g * (PIX / 4)];
    const float4 a1 = xn[(size_t)(g + 8) * (PIX / 4)];

    // ---- threshold partials: thr = max_o( sum_{c<16}|w[o,c,1,:]| + b[o] ) ----
    // (w center-tap footprint ~80KB -> L1/L2 resident, reused by all blocks)
    {
        const int o = tid >> 2, jj = tid & 3;    // 64 o x 4 threads (4 ch each)
        float s = 0.f;
        #pragma unroll
        for (int k = 0; k < 4; ++k) {
            const float* wp = w + (size_t)o * 576 + (jj * 4 + k) * 9 + 3;  // kh=1
            s += fabsf(wp[0]) + fabsf(wp[1]) + fabsf(wp[2]);
        }
        s += __shfl_xor(s, 1); s += __shfl_xor(s, 2);
        float v = s + b[o];
        #pragma unroll
        for (int d = 4; d < 64; d <<= 1) v = fmaxf(v, __shfl_xor(v, d));
        if ((tid & 63) == 0) wmax[tid >> 6] = v;
    }

    // ---- A16 partials -> LDS ----
    {
        float4 a;
        a.x = fabsf(a0.x) + fabsf(a1.x); a.y = fabsf(a0.y) + fabsf(a1.y);
        a.z = fabsf(a0.z) + fabsf(a1.z); a.w = fabsf(a0.w) + fabsf(a1.w);
        *(float4*)&Ap[g * 128 + c4 * 4] = a;
    }
    __syncthreads();   // the ONLY barrier (even blocks: also drains early stores)

    const float thr = fmaxf(fmaxf(wmax[0], wmax[1]),
                            fmaxf(wmax[2], wmax[3])) + 1.0f;

    // ---- screen: lane -> col = wid*32 + (lane&31); halves split g 0-3 / 4-7 ----
    const int col = wid * 32 + (lane & 31);
    const int hf  = lane >> 5;
    float S = 0.f;
    #pragma unroll
    for (int gg = 0; gg < 4; ++gg) {
        const float* ap = &Ap[(hf * 4 + gg) * 128 + col];
        float sv = ap[0];
        if (col > 0)   sv += ap[-1];
        if (col < 127) sv += ap[1];
        S += sv;
    }
    S += __shfl_xor(S, 32);          // combine halves: full A16 box-sum
    const bool fail = !(S >= thr);   // cannot prove zero
    const u64 bal = __ballot(fail);

    if (!even) do_stores();          // late write stream; no barrier after

    // ---- exact fp32 fix-up, per wave (normally never taken) ----
    if (bal) {
        asm volatile("s_waitcnt vmcnt(0)" ::: "memory");  // order vs own zeros
        u32 m = (u32)(bal & 0xffffffffu);   // bits 32..63 duplicate 0..31
        const float* xs = x + (size_t)n * C_IN * PIX;
        while (m) {
            const int bit = __ffs(m) - 1;
            m &= m - 1;
            const int fcol = wid * 32 + bit;
            const int o = lane;              // 64 lanes = 64 outputs
            const float* wo = w + (size_t)o * C_IN * 9;
            float sum = 0.f;
            for (int c = 0; c < C_IN; ++c) {
                const float* xc = xs + (size_t)c * PIX;
                const float* wc = wo + c * 9;
                #pragma unroll
                for (int kh = 0; kh < 3; ++kh) {
                    const int gh = h + kh - 1;
                    #pragma unroll
                    for (int kw = 0; kw < 3; ++kw) {
                        const int gw = fcol + kw - 1;
                        const float xval = ((unsigned)gh < (unsigned)Hh &&
                                            (unsigned)gw < (unsigned)Ww)
                                           ? xc[gh * Ww + gw] : 0.f;
                        sum += fabsf(xval - wc[kh * 3 + kw]);
                    }
                }
            }
            out[(size_t)(n * O_OUT + o) * PIX + h * Ww + fcol] = fmaxf(b[o] - sum, 0.f);
        }
    }
}

extern "C" void kernel_launch(void* const* d_in, const int* in_sizes, int n_in,
                              void* d_out, int out_size, void* d_ws, size_t ws_size,
                              hipStream_t stream) {
    const float* x = (const float*)d_in[0];
    const float* w = (const float*)d_in[1];
    const float* b = (const float*)d_in[2];
    float* out = (float*)d_out;

    adder_row_screen<<<NB * Hh, 256, 0, stream>>>(x, w, b, out);
}